// Round 9
// baseline (170.607 us; speedup 1.0000x reference)
//
#include <hip/hip_runtime.h>

#define NGRAPHS 64
#define NCLS 32
#define G1 256   // partition blocks (fixed: scan grid is 256*256)

// pack two f32 -> one uint of two bf16 (RTN-even)
__device__ inline unsigned bfpack(float lo, float hi) {
    unsigned ulo = __float_as_uint(lo); ulo += 0x7fffu + ((ulo >> 16) & 1u);
    unsigned uhi = __float_as_uint(hi); uhi += 0x7fffu + ((uhi >> 16) & 1u);
    return (ulo >> 16) | (uhi & 0xffff0000u);
}
__device__ inline float bflo(unsigned p) { return __uint_as_float(p << 16); }
__device__ inline float bfhi(unsigned p) { return __uint_as_float(p & 0xffff0000u); }
__device__ inline float bfs(unsigned short u) { return __uint_as_float((unsigned)u << 16); }

// ---- S1+S3 fused: per-block bucket histogram, block-local offsets, and
// scatter into the block's OWN chunk window. Second pass over the chunk is
// L1/L2-hot (~47KB). gHd/gHs written for the global scan (bucket CSR layout).
__global__ __launch_bounds__(256) void part_hist_scatter(
    const float* __restrict__ eh, const int* __restrict__ src,
    const int* __restrict__ dst, const float* __restrict__ mu,
    const float* __restrict__ sigma, int* __restrict__ gHd,
    int* __restrict__ gHs, int* __restrict__ gLocD, int* __restrict__ gLocS,
    int2* __restrict__ partD, unsigned char* __restrict__ partS, int nE) {
    __shared__ int hd[256], hs[256], tmp[256], locD[256], locS[256];
    int t = threadIdx.x, blk = blockIdx.x;
    hd[t] = 0; hs[t] = 0;
    __syncthreads();
    int chunk = (nE + G1 - 1) / G1;
    int beg = blk * chunk, end = min(beg + chunk, nE);
    for (int i = beg + t; i < end; i += 256) {
        atomicAdd(&hd[((unsigned)dst[i]) >> 8], 1);
        atomicAdd(&hs[((unsigned)src[i]) >> 8], 1);
    }
    __syncthreads();
    gHd[t * G1 + blk] = hd[t];
    gHs[t * G1 + blk] = hs[t];
    // block-local exclusive scan of hd
    tmp[t] = hd[t];
    __syncthreads();
    for (int o = 1; o < 256; o <<= 1) {
        int u = (t >= o) ? tmp[t - o] : 0;
        __syncthreads();
        tmp[t] += u;
        __syncthreads();
    }
    locD[t] = tmp[t] - hd[t];
    gLocD[blk * 256 + t] = locD[t];
    __syncthreads();
    // block-local exclusive scan of hs
    tmp[t] = hs[t];
    __syncthreads();
    for (int o = 1; o < 256; o <<= 1) {
        int u = (t >= o) ? tmp[t - o] : 0;
        __syncthreads();
        tmp[t] += u;
        __syncthreads();
    }
    locS[t] = tmp[t] - hs[t];
    gLocS[blk * 256 + t] = locS[t];
    // reset counters for ticketing
    hd[t] = 0; hs[t] = 0;
    __syncthreads();
    float mu0 = mu[0], inv = -1.f / sigma[0];
    size_t wbase = (size_t)blk * chunk;
    for (int i = beg + t; i < end; i += 256) {   // chunk is cache-hot now
        int d = dst[i], s = src[i];
        float df = eh[i] - mu0;
        float w = logf(df * df * inv);
        int bu = ((unsigned)d) >> 8;
        int r = atomicAdd(&hd[bu], 1);
        partD[wbase + locD[bu] + r] = make_int2((s << 8) | (d & 255), __float_as_int(w));
        int bs = ((unsigned)s) >> 8;
        int r2 = atomicAdd(&hs[bs], 1);
        partS[wbase + locS[bs] + r2] = (unsigned char)(s & 255);
    }
}

// ---- S2: exclusive scan of the two 65536-entry grids (2 blocks, in place).
// Block 0's spare lanes also zero the fused-pool accumulator (poisoned ws).
__global__ __launch_bounds__(1024) void part_scan(int* __restrict__ a,
    int* __restrict__ b, float* __restrict__ gout) {
    __shared__ int part[1024];
    int t = threadIdx.x;
    if (blockIdx.x == 0) {
        gout[t] = 0.f; gout[t + 1024] = 0.f;   // NGRAPHS*NCLS = 2048
    }
    int* arr = blockIdx.x ? b : a;
    int base = t * 64;
    int v[64], s = 0;
#pragma unroll
    for (int j = 0; j < 64; ++j) { v[j] = arr[base + j]; s += v[j]; }
    part[t] = s;
    __syncthreads();
    for (int o = 1; o < 1024; o <<= 1) {
        int u = (t >= o) ? part[t - o] : 0;
        __syncthreads();
        part[t] += u;
        __syncthreads();
    }
    int run = part[t] - s;   // exclusive
#pragma unroll
    for (int j = 0; j < 64; ++j) { arr[base + j] = run; run += v[j]; }
    if (t == 1023) arr[65536] = run;
}

// ---- S4: per-bucket CSR build. Thread t walks block-t's run for this bucket.
// Run walks use 4/8-wide clamped load batches so L2/L3 latency overlaps.
__global__ __launch_bounds__(256) void bucket_build(const int2* __restrict__ partD,
    const unsigned char* __restrict__ partS, const int* __restrict__ gHd,
    const int* __restrict__ gHs, const int* __restrict__ gLocD,
    const int* __restrict__ gLocS, int* __restrict__ csr_src,
    unsigned short* __restrict__ csr_w, int* __restrict__ row_start,
    float* __restrict__ norm_dst, float* __restrict__ norm_src, int nN, int nE) {
    __shared__ int deg[256], loff[256], cnt[256];
    int b = blockIdx.x, t = threadIdx.x;
    int chunk = (nE + G1 - 1) / G1;
    int begD = gHd[b * G1];
    int lenD = gHd[b * G1 + t + 1] - gHd[b * G1 + t];
    size_t offD = (size_t)t * chunk + gLocD[t * 256 + b];
    deg[t] = 0; cnt[t] = 0;
    __syncthreads();
    for (int i = 0; i < lenD; i += 4) {          // batched: 4 loads in flight
        int lo4[4];
#pragma unroll
        for (int u = 0; u < 4; ++u)
            lo4[u] = partD[offD + min(i + u, lenD - 1)].x & 255;
#pragma unroll
        for (int u = 0; u < 4; ++u)
            if (i + u < lenD) atomicAdd(&deg[lo4[u]], 1);
    }
    __syncthreads();
    loff[t] = deg[t];
    __syncthreads();
    for (int o = 1; o < 256; o <<= 1) {
        int u = (t >= o) ? loff[t - o] : 0;
        __syncthreads();
        loff[t] += u;
        __syncthreads();
    }
    loff[t] -= deg[t];
    __syncthreads();
    int n = b * 256 + t;
    if (n < nN) {
        row_start[n] = begD + loff[t];
        norm_dst[n] = rsqrtf((float)max(deg[t], 1));
    }
    if (b == 0 && t == 0) row_start[nN] = nE;
    for (int i = 0; i < lenD; i += 4) {          // batched placement pass
        int2 r4[4];
#pragma unroll
        for (int u = 0; u < 4; ++u)
            r4[u] = partD[offD + min(i + u, lenD - 1)];
#pragma unroll
        for (int u = 0; u < 4; ++u) {
            if (i + u < lenD) {
                int lo = r4[u].x & 255;
                int pos = atomicAdd(&cnt[lo], 1);
                int idx = begD + loff[lo] + pos;
                csr_src[idx] = r4[u].x >> 8;
                unsigned uw = (unsigned)r4[u].y;
                csr_w[idx] = (unsigned short)((uw + 0x7fffu + ((uw >> 16) & 1u)) >> 16);
            }
        }
    }
    // ---- src side: per-run byte counts -> norm_src ----
    __syncthreads();
    deg[t] = 0;
    __syncthreads();
    int lenS = gHs[b * G1 + t + 1] - gHs[b * G1 + t];
    size_t offS = (size_t)t * chunk + gLocS[t * 256 + b];
    for (int i = 0; i < lenS; i += 8) {          // batched: 8 byte-loads in flight
        int v8[8];
#pragma unroll
        for (int u = 0; u < 8; ++u)
            v8[u] = partS[offS + min(i + u, lenS - 1)];
#pragma unroll
        for (int u = 0; u < 8; ++u)
            if (i + u < lenS) atomicAdd(&deg[v8[u]], 1);
    }
    __syncthreads();
    if (n < nN) norm_src[n] = rsqrtf((float)max(deg[t], 1));
}

// xw[n] = bf16( (x[n]*norm_src[n]) @ W1 )
__global__ __launch_bounds__(256) void xw_mm(const float* __restrict__ x,
    const float* __restrict__ norm_src, const float* __restrict__ W1,
    unsigned* __restrict__ xw, int nN) {
    __shared__ float sW[64 * 64];
    __shared__ float srow[4][64];
    int t = threadIdx.x;
    for (int i = t; i < 64 * 64; i += 256) sW[i] = W1[i];
    __syncthreads();
    int wid = t >> 6, k = t & 63;
    int base = blockIdx.x * 32;
    for (int it = 0; it < 8; ++it) {
        int n = base + it * 4 + wid;
        if (n >= nN) break;
        srow[wid][k] = x[((size_t)n << 6) + k] * norm_src[n];
        float acc0 = 0.f, acc1 = 0.f;
#pragma unroll
        for (int i = 0; i < 64; i += 2) {
            acc0 += srow[wid][i] * sW[i * 64 + k];
            acc1 += srow[wid][i + 1] * sW[(i + 1) * 64 + k];
        }
        float outv = acc0 + acc1;
        float other = __shfl_xor(outv, 1, 64);
        if ((k & 1) == 0) xw[((size_t)n << 5) + (k >> 1)] = bfpack(outv, other);
    }
}

// ---------------------------------------------------------------------------
// Fused layer1 gather + layer2 dense, 4-deep software pipeline: ALL 4 nodes'
// csr batches then ALL 4 gather batches issued in the prologue, so node k's
// data is in flight for k full processing phases (~1800cy for node3) before
// use — covers L3/HBM gather latency that the 2-deep schedule exposed.
// Quarter-wave per edge (16 lanes x uint2 = 128B row), 24-edge clamped
// batches, serial remainder for long rows.
// ---------------------------------------------------------------------------
#define LCSR(P, bg, en) { \
    int last_ = max((en) - 1, 0); \
    _Pragma("unroll") \
    for (int u = 0; u < 6; ++u) { \
        int sl = (bg) + q + 4 * u; \
        int slc = (sl < (en)) ? sl : last_; \
        P##s[u] = csr_src[slc]; \
        float wv = bfs(csr_w[slc]); \
        P##w[u] = (sl < (en)) ? wv : 0.f; \
    } }
#define LGAT(P) { \
    _Pragma("unroll") \
    for (int u = 0; u < 6; ++u) P##p[u] = xw2[((size_t)P##s[u] << 4) + j]; }
#define LFMA(P) { \
    _Pragma("unroll") \
    for (int u = 0; u < 6; ++u) { \
        a0 += P##w[u] * bflo(P##p[u].x); a1 += P##w[u] * bfhi(P##p[u].x); \
        a2 += P##w[u] * bflo(P##p[u].y); a3 += P##w[u] * bfhi(P##p[u].y); } }
#define REM(P, bg, en) { \
    for (int sl0 = (bg) + q + 24; sl0 < (en); sl0 += 24) { \
        int last_ = (en) - 1; \
        _Pragma("unroll") \
        for (int u = 0; u < 6; ++u) { \
            int sl = sl0 + 4 * u; \
            int slc = (sl < (en)) ? sl : last_; \
            P##s[u] = csr_src[slc]; \
            float wv = bfs(csr_w[slc]); \
            P##w[u] = (sl < (en)) ? wv : 0.f; } \
        _Pragma("unroll") \
        for (int u = 0; u < 6; ++u) P##p[u] = xw2[((size_t)P##s[u] << 4) + j]; \
        LFMA(P) } }
#define EPI(nd_, ns_, n_) { \
    a0 += __shfl_xor(a0, 16, 64); a0 += __shfl_xor(a0, 32, 64); \
    a1 += __shfl_xor(a1, 16, 64); a1 += __shfl_xor(a1, 32, 64); \
    a2 += __shfl_xor(a2, 16, 64); a2 += __shfl_xor(a2, 32, 64); \
    a3 += __shfl_xor(a3, 16, 64); a3 += __shfl_xor(a3, 32, 64); \
    if (q == 0) { \
        float4 v; \
        v.x = fmaxf(a0 * (nd_) + bv.x, 0.f) * (ns_); \
        v.y = fmaxf(a1 * (nd_) + bv.y, 0.f) * (ns_); \
        v.z = fmaxf(a2 * (nd_) + bv.z, 0.f) * (ns_); \
        v.w = fmaxf(a3 * (nd_) + bv.w, 0.f) * (ns_); \
        *reinterpret_cast<float4*>(&srow[wid][4 * j]) = v; } \
    { int jj = lane & 31, ib = lane & 32; \
      float c0 = 0.f, c1 = 0.f; \
      _Pragma("unroll") \
      for (int i = 0; i < 32; i += 2) { \
          c0 += srow[wid][ib + i] * sW[(ib + i) * NCLS + jj]; \
          c1 += srow[wid][ib + i + 1] * sW[(ib + i + 1) * NCLS + jj]; } \
      float part = c0 + c1; \
      part += __shfl_xor(part, 32, 64); \
      float other = __shfl_xor(part, 1, 64); \
      if (ib == 0 && (jj & 1) == 0 && (n_) < nN) \
          hw[((size_t)(n_) << 4) + (jj >> 1)] = bfpack(part, other); } }

__global__ __launch_bounds__(256) void gather1_mm(const unsigned* __restrict__ xw,
    const int* __restrict__ row_start, const int* __restrict__ csr_src,
    const unsigned short* __restrict__ csr_w, const float* __restrict__ norm_dst,
    const float* __restrict__ norm_src, const float* __restrict__ W2f,
    const float* __restrict__ b1, unsigned* __restrict__ hw, int nN) {
    __shared__ float sW[64 * NCLS];
    __shared__ float srow[4][64];
    __shared__ int rs[17];
    int t = threadIdx.x;
    int base = blockIdx.x * 16;
    for (int i = t; i < 64 * NCLS; i += 256) sW[i] = W2f[i];
    if (t < 17) rs[t] = row_start[min(base + t, nN)];
    __syncthreads();
    int wid = t >> 6, lane = t & 63;
    int q = lane >> 4, j = lane & 15;        // quarter-wave edge groups
    const uint2* xw2 = reinterpret_cast<const uint2*>(xw);
    float4 bv = reinterpret_cast<const float4*>(b1)[j];   // b1[4j..4j+3]
    int n0 = base + wid, n1 = n0 + 4, n2 = n0 + 8, n3 = n0 + 12;
    int nc = nN - 1;
    // hoisted per-node norms: off the critical path
    float nd0 = norm_dst[min(n0, nc)], ns0 = norm_src[min(n0, nc)];
    float nd1 = norm_dst[min(n1, nc)], ns1 = norm_src[min(n1, nc)];
    float nd2 = norm_dst[min(n2, nc)], ns2 = norm_src[min(n2, nc)];
    float nd3 = norm_dst[min(n3, nc)], ns3 = norm_src[min(n3, nc)];
    int r0b = __builtin_amdgcn_readfirstlane(rs[wid]);
    int r0e = __builtin_amdgcn_readfirstlane(rs[wid + 1]);
    int r1b = __builtin_amdgcn_readfirstlane(rs[wid + 4]);
    int r1e = __builtin_amdgcn_readfirstlane(rs[wid + 5]);
    int r2b = __builtin_amdgcn_readfirstlane(rs[wid + 8]);
    int r2e = __builtin_amdgcn_readfirstlane(rs[wid + 9]);
    int r3b = __builtin_amdgcn_readfirstlane(rs[wid + 12]);
    int r3e = __builtin_amdgcn_readfirstlane(rs[wid + 13]);
    int As[6]; float Aw[6]; uint2 Ap[6];
    int Bs[6]; float Bw[6]; uint2 Bp[6];
    int Cs[6]; float Cw[6]; uint2 Cp[6];
    int Ds[6]; float Dw[6]; uint2 Dp[6];
    float a0, a1, a2, a3;
    // 4-deep prologue: all csr batches, then all gather batches, in flight
    LCSR(A, r0b, r0e)
    LCSR(B, r1b, r1e)
    LCSR(C, r2b, r2e)
    LCSR(D, r3b, r3e)
    LGAT(A)
    LGAT(B)
    LGAT(C)
    LGAT(D)
    // node0
    a0 = a1 = a2 = a3 = 0.f;
    LFMA(A)
    REM(A, r0b, r0e)
    EPI(nd0, ns0, n0)
    // node1
    a0 = a1 = a2 = a3 = 0.f;
    LFMA(B)
    REM(B, r1b, r1e)
    EPI(nd1, ns1, n1)
    // node2
    a0 = a1 = a2 = a3 = 0.f;
    LFMA(C)
    REM(C, r2b, r2e)
    EPI(nd2, ns2, n2)
    // node3
    a0 = a1 = a2 = a3 = 0.f;
    LFMA(D)
    REM(D, r3b, r3e)
    EPI(nd3, ns3, n3)
}

// ---------------------------------------------------------------------------
// gather2 + pool accumulate, 4-deep pipeline (same prologue structure).
// Per-node agg goes straight into a per-block [64][32] LDS graph accumulator
// (f32 LDS atomics), flushed with device-scope global atomicAdd. NO fence,
// NO ticket (round-6 lesson). Finalization in a separate tiny kernel.
// Eighth-wave per edge (8 lanes x uint2 = 64B row), 24-edge clamped batches.
// ---------------------------------------------------------------------------
#define LCSR2(P, bg, en) { \
    int last_ = max((en) - 1, 0); \
    _Pragma("unroll") \
    for (int u = 0; u < 3; ++u) { \
        int sl = (bg) + o + 8 * u; \
        int slc = (sl < (en)) ? sl : last_; \
        P##s[u] = csr_src[slc]; \
        float wv = bfs(csr_w[slc]); \
        P##w[u] = (sl < (en)) ? wv : 0.f; \
    } }
#define LGAT2(P) { \
    _Pragma("unroll") \
    for (int u = 0; u < 3; ++u) P##p[u] = hw2[((size_t)P##s[u] << 3) + j]; }
#define LFMA2(P) { \
    _Pragma("unroll") \
    for (int u = 0; u < 3; ++u) { \
        a0 += P##w[u] * bflo(P##p[u].x); a1 += P##w[u] * bfhi(P##p[u].x); \
        a2 += P##w[u] * bflo(P##p[u].y); a3 += P##w[u] * bfhi(P##p[u].y); } }
#define REM2(P, bg, en) { \
    for (int sl0 = (bg) + o + 24; sl0 < (en); sl0 += 24) { \
        int last_ = (en) - 1; \
        _Pragma("unroll") \
        for (int u = 0; u < 3; ++u) { \
            int sl = sl0 + 8 * u; \
            int slc = (sl < (en)) ? sl : last_; \
            P##s[u] = csr_src[slc]; \
            float wv = bfs(csr_w[slc]); \
            P##w[u] = (sl < (en)) ? wv : 0.f; } \
        _Pragma("unroll") \
        for (int u = 0; u < 3; ++u) P##p[u] = hw2[((size_t)P##s[u] << 3) + j]; \
        LFMA2(P) } }
#define EPI2(nd_, g_, n_) { \
    a0 += __shfl_xor(a0, 8, 64); a0 += __shfl_xor(a0, 16, 64); a0 += __shfl_xor(a0, 32, 64); \
    a1 += __shfl_xor(a1, 8, 64); a1 += __shfl_xor(a1, 16, 64); a1 += __shfl_xor(a1, 32, 64); \
    a2 += __shfl_xor(a2, 8, 64); a2 += __shfl_xor(a2, 16, 64); a2 += __shfl_xor(a2, 32, 64); \
    a3 += __shfl_xor(a3, 8, 64); a3 += __shfl_xor(a3, 16, 64); a3 += __shfl_xor(a3, 32, 64); \
    if (lane < 8 && (n_) < nN) { \
        atomicAdd(&gacc[(g_) * NCLS + 4 * j + 0], a0 * (nd_)); \
        atomicAdd(&gacc[(g_) * NCLS + 4 * j + 1], a1 * (nd_)); \
        atomicAdd(&gacc[(g_) * NCLS + 4 * j + 2], a2 * (nd_)); \
        atomicAdd(&gacc[(g_) * NCLS + 4 * j + 3], a3 * (nd_)); } }

__global__ __launch_bounds__(256) void gather2_acc(const unsigned* __restrict__ hw,
    const int* __restrict__ row_start, const int* __restrict__ csr_src,
    const unsigned short* __restrict__ csr_w, const float* __restrict__ norm_dst,
    const int* __restrict__ ng, float* __restrict__ gout, int nN) {
    __shared__ float gacc[NGRAPHS * NCLS];   // 8KB per-block graph accumulator
    __shared__ int rs[17];
    int t = threadIdx.x;
    int base = blockIdx.x * 16;
    for (int i = t; i < NGRAPHS * NCLS; i += 256) gacc[i] = 0.f;
    if (t < 17) rs[t] = row_start[min(base + t, nN)];
    __syncthreads();
    int wid = t >> 6, lane = t & 63;
    int o = lane >> 3, j = lane & 7;         // eighth-wave edge groups
    const uint2* hw2 = reinterpret_cast<const uint2*>(hw);
    int n0 = base + wid, n1 = n0 + 4, n2 = n0 + 8, n3 = n0 + 12;
    int nc = nN - 1;
    float nd0 = norm_dst[min(n0, nc)], nd1 = norm_dst[min(n1, nc)];
    float nd2 = norm_dst[min(n2, nc)], nd3 = norm_dst[min(n3, nc)];
    int g0 = ng[min(n0, nc)], g1 = ng[min(n1, nc)];
    int g2 = ng[min(n2, nc)], g3 = ng[min(n3, nc)];
    int r0b = __builtin_amdgcn_readfirstlane(rs[wid]);
    int r0e = __builtin_amdgcn_readfirstlane(rs[wid + 1]);
    int r1b = __builtin_amdgcn_readfirstlane(rs[wid + 4]);
    int r1e = __builtin_amdgcn_readfirstlane(rs[wid + 5]);
    int r2b = __builtin_amdgcn_readfirstlane(rs[wid + 8]);
    int r2e = __builtin_amdgcn_readfirstlane(rs[wid + 9]);
    int r3b = __builtin_amdgcn_readfirstlane(rs[wid + 12]);
    int r3e = __builtin_amdgcn_readfirstlane(rs[wid + 13]);
    int As[3]; float Aw[3]; uint2 Ap[3];
    int Bs[3]; float Bw[3]; uint2 Bp[3];
    int Cs[3]; float Cw[3]; uint2 Cp[3];
    int Ds[3]; float Dw[3]; uint2 Dp[3];
    float a0, a1, a2, a3;
    // 4-deep prologue
    LCSR2(A, r0b, r0e)
    LCSR2(B, r1b, r1e)
    LCSR2(C, r2b, r2e)
    LCSR2(D, r3b, r3e)
    LGAT2(A)
    LGAT2(B)
    LGAT2(C)
    LGAT2(D)
    // node0
    a0 = a1 = a2 = a3 = 0.f;
    LFMA2(A)
    REM2(A, r0b, r0e)
    EPI2(nd0, g0, n0)
    // node1
    a0 = a1 = a2 = a3 = 0.f;
    LFMA2(B)
    REM2(B, r1b, r1e)
    EPI2(nd1, g1, n1)
    // node2
    a0 = a1 = a2 = a3 = 0.f;
    LFMA2(C)
    REM2(C, r2b, r2e)
    EPI2(nd2, g2, n2)
    // node3
    a0 = a1 = a2 = a3 = 0.f;
    LFMA2(D)
    REM2(D, r3b, r3e)
    EPI2(nd3, g3, n3)
    // ---- flush nonzero cells (device-scope atomics; no fence, no ticket) ----
    __syncthreads();
    for (int i = t; i < NGRAPHS * NCLS; i += 256) {
        float v = gacc[i];
        if (v != 0.f) atomicAdd(&gout[i], v);
    }
}

// finalize: tiny 1-block kernel after gather2_acc completes (stream boundary
// gives cross-XCD visibility of the atomic sums).
__global__ __launch_bounds__(256) void finalize_out(const float* __restrict__ gout,
    const int* __restrict__ ng, const float* __restrict__ b2,
    float* __restrict__ out, int nN) {
    __shared__ int cnts[NGRAPHS];
    int t = threadIdx.x;
    if (t < NGRAPHS) {
        int g = t;
        int lo = 0, hi = nN;
        while (lo < hi) { int m = (lo + hi) >> 1; if (ng[m] < g) lo = m + 1; else hi = m; }
        int lb = lo;
        lo = 0; hi = nN;
        while (lo < hi) { int m = (lo + hi) >> 1; if (ng[m] < g + 1) lo = m + 1; else hi = m; }
        cnts[g] = lo - lb;
    }
    __syncthreads();
    for (int i = t; i < NGRAPHS * NCLS; i += 256) {
        int g = i >> 5, f = i & 31;
        float cnt = (float)cnts[g];
        out[i] = (gout[i] + b2[f] * cnt) / fmaxf(cnt, 1.f);
    }
}

extern "C" void kernel_launch(void* const* d_in, const int* in_sizes, int n_in,
                              void* d_out, int out_size, void* d_ws, size_t ws_size,
                              hipStream_t stream) {
    const float* x   = (const float*)d_in[0];
    const float* eh  = (const float*)d_in[1];
    const int*   src = (const int*)d_in[2];
    const int*   dst = (const int*)d_in[3];
    const int*   ng  = (const int*)d_in[4];
    const float* W1  = (const float*)d_in[5];
    const float* b1  = (const float*)d_in[6];
    const float* W2  = (const float*)d_in[7];
    const float* b2  = (const float*)d_in[8];
    const float* mu  = (const float*)d_in[9];
    const float* sg  = (const float*)d_in[10];
    const int nN = in_sizes[0] / 64;
    const int nE = in_sizes[1];
    const int NBUK = (nN + 255) / 256;
    const int chunk = (nE + G1 - 1) / G1;

    // Workspace. Every cell read is written first (gout zeroed in part_scan).
    char* wsb = (char*)d_ws;
    int* gHd = (int*)wsb;                                 // 65537
    int* gHs = gHd + 65537;                               // 65537
    int* gLocD = gHs + 65537;                             // 65536
    int* gLocS = gLocD + 65536;                           // 65536
    int* row_start = gLocS + 65536;                       // nN+1
    float* norm_src = (float*)(row_start + nN + 1);       // nN
    float* norm_dst = norm_src + nN;                      // nN
    float* gout = norm_dst + nN;                          // 64*32
    size_t off = (size_t)((char*)(gout + NGRAPHS * NCLS) - wsb);
    off = (off + 15) & ~(size_t)15;
    int2* partD = (int2*)(wsb + off);                     // G1*chunk int2
    unsigned char* partS = (unsigned char*)(partD + (size_t)G1 * chunk); // G1*chunk
    off = (size_t)((char*)(partS + (size_t)G1 * chunk) - wsb);
    off = (off + 15) & ~(size_t)15;
    int* csr_src = (int*)(wsb + off);                     // nE
    unsigned short* csr_w = (unsigned short*)(csr_src + nE); // nE
    off = (size_t)((char*)(csr_w + nE) - wsb);
    off = (off + 15) & ~(size_t)15;
    unsigned* xw   = (unsigned*)(wsb + off);              // nN*32
    unsigned* hw   = xw + (size_t)nN * 32;                // nN*16

    part_hist_scatter<<<G1, 256, 0, stream>>>(eh, src, dst, mu, sg, gHd, gHs,
                                              gLocD, gLocS, partD, partS, nE);
    part_scan<<<2, 1024, 0, stream>>>(gHd, gHs, gout);
    bucket_build<<<NBUK, 256, 0, stream>>>(partD, partS, gHd, gHs, gLocD, gLocS,
                                           csr_src, csr_w, row_start,
                                           norm_dst, norm_src, nN, nE);
    xw_mm<<<(nN + 31) / 32, 256, 0, stream>>>(x, norm_src, W1, xw, nN);
    gather1_mm<<<(nN + 15) / 16, 256, 0, stream>>>(xw, row_start, csr_src, csr_w,
                                                   norm_dst, norm_src, W2, b1, hw, nN);
    gather2_acc<<<(nN + 15) / 16, 256, 0, stream>>>(hw, row_start, csr_src, csr_w,
                                                    norm_dst, ng, gout, nN);
    finalize_out<<<1, 256, 0, stream>>>(gout, ng, b2, (float*)d_out, nN);

    (void)n_in; (void)out_size; (void)ws_size;
}

// Round 10
// 160.625 us; speedup vs baseline: 1.0621x; 1.0621x over previous
//
#include <hip/hip_runtime.h>

#define NGRAPHS 64
#define NCLS 32
#define G1 256   // partition blocks (fixed: scan grid is 256*256)

// pack two f32 -> one uint of two bf16 (RTN-even)
__device__ inline unsigned bfpack(float lo, float hi) {
    unsigned ulo = __float_as_uint(lo); ulo += 0x7fffu + ((ulo >> 16) & 1u);
    unsigned uhi = __float_as_uint(hi); uhi += 0x7fffu + ((uhi >> 16) & 1u);
    return (ulo >> 16) | (uhi & 0xffff0000u);
}
__device__ inline float bflo(unsigned p) { return __uint_as_float(p << 16); }
__device__ inline float bfhi(unsigned p) { return __uint_as_float(p & 0xffff0000u); }
__device__ inline float bfs(unsigned short u) { return __uint_as_float((unsigned)u << 16); }

// ---- S1+S3 fused: per-block bucket histogram, block-local offsets, and
// scatter into the block's OWN chunk window. Second pass over the chunk is
// L1/L2-hot (~47KB). gHd/gHs written for the global scan (bucket CSR layout).
__global__ __launch_bounds__(256) void part_hist_scatter(
    const float* __restrict__ eh, const int* __restrict__ src,
    const int* __restrict__ dst, const float* __restrict__ mu,
    const float* __restrict__ sigma, int* __restrict__ gHd,
    int* __restrict__ gHs, int* __restrict__ gLocD, int* __restrict__ gLocS,
    int2* __restrict__ partD, unsigned char* __restrict__ partS, int nE) {
    __shared__ int hd[256], hs[256], tmp[256], locD[256], locS[256];
    int t = threadIdx.x, blk = blockIdx.x;
    hd[t] = 0; hs[t] = 0;
    __syncthreads();
    int chunk = (nE + G1 - 1) / G1;
    int beg = blk * chunk, end = min(beg + chunk, nE);
    for (int i = beg + t; i < end; i += 256) {
        atomicAdd(&hd[((unsigned)dst[i]) >> 8], 1);
        atomicAdd(&hs[((unsigned)src[i]) >> 8], 1);
    }
    __syncthreads();
    gHd[t * G1 + blk] = hd[t];
    gHs[t * G1 + blk] = hs[t];
    // block-local exclusive scan of hd
    tmp[t] = hd[t];
    __syncthreads();
    for (int o = 1; o < 256; o <<= 1) {
        int u = (t >= o) ? tmp[t - o] : 0;
        __syncthreads();
        tmp[t] += u;
        __syncthreads();
    }
    locD[t] = tmp[t] - hd[t];
    gLocD[blk * 256 + t] = locD[t];
    __syncthreads();
    // block-local exclusive scan of hs
    tmp[t] = hs[t];
    __syncthreads();
    for (int o = 1; o < 256; o <<= 1) {
        int u = (t >= o) ? tmp[t - o] : 0;
        __syncthreads();
        tmp[t] += u;
        __syncthreads();
    }
    locS[t] = tmp[t] - hs[t];
    gLocS[blk * 256 + t] = locS[t];
    // reset counters for ticketing
    hd[t] = 0; hs[t] = 0;
    __syncthreads();
    float mu0 = mu[0], inv = -1.f / sigma[0];
    size_t wbase = (size_t)blk * chunk;
    for (int i = beg + t; i < end; i += 256) {   // chunk is cache-hot now
        int d = dst[i], s = src[i];
        float df = eh[i] - mu0;
        float w = logf(df * df * inv);
        int bu = ((unsigned)d) >> 8;
        int r = atomicAdd(&hd[bu], 1);
        partD[wbase + locD[bu] + r] = make_int2((s << 8) | (d & 255), __float_as_int(w));
        int bs = ((unsigned)s) >> 8;
        int r2 = atomicAdd(&hs[bs], 1);
        partS[wbase + locS[bs] + r2] = (unsigned char)(s & 255);
    }
}

// ---- S2: exclusive scan of the two 65536-entry grids (2 blocks, in place).
// Block 0's spare lanes also zero the fused-pool accumulator (poisoned ws).
__global__ __launch_bounds__(1024) void part_scan(int* __restrict__ a,
    int* __restrict__ b, float* __restrict__ gout) {
    __shared__ int part[1024];
    int t = threadIdx.x;
    if (blockIdx.x == 0) {
        gout[t] = 0.f; gout[t + 1024] = 0.f;   // NGRAPHS*NCLS = 2048
    }
    int* arr = blockIdx.x ? b : a;
    int base = t * 64;
    int v[64], s = 0;
#pragma unroll
    for (int j = 0; j < 64; ++j) { v[j] = arr[base + j]; s += v[j]; }
    part[t] = s;
    __syncthreads();
    for (int o = 1; o < 1024; o <<= 1) {
        int u = (t >= o) ? part[t - o] : 0;
        __syncthreads();
        part[t] += u;
        __syncthreads();
    }
    int run = part[t] - s;   // exclusive
#pragma unroll
    for (int j = 0; j < 64; ++j) { arr[base + j] = run; run += v[j]; }
    if (t == 1023) arr[65536] = run;
}

// ---- S4: per-bucket CSR build. Thread t walks block-t's run for this bucket.
// Run walks use 4/8-wide clamped load batches so L2/L3 latency overlaps.
__global__ __launch_bounds__(256) void bucket_build(const int2* __restrict__ partD,
    const unsigned char* __restrict__ partS, const int* __restrict__ gHd,
    const int* __restrict__ gHs, const int* __restrict__ gLocD,
    const int* __restrict__ gLocS, int* __restrict__ csr_src,
    unsigned short* __restrict__ csr_w, int* __restrict__ row_start,
    float* __restrict__ norm_dst, float* __restrict__ norm_src, int nN, int nE) {
    __shared__ int deg[256], loff[256], cnt[256];
    int b = blockIdx.x, t = threadIdx.x;
    int chunk = (nE + G1 - 1) / G1;
    int begD = gHd[b * G1];
    int lenD = gHd[b * G1 + t + 1] - gHd[b * G1 + t];
    size_t offD = (size_t)t * chunk + gLocD[t * 256 + b];
    deg[t] = 0; cnt[t] = 0;
    __syncthreads();
    for (int i = 0; i < lenD; i += 4) {          // batched: 4 loads in flight
        int lo4[4];
#pragma unroll
        for (int u = 0; u < 4; ++u)
            lo4[u] = partD[offD + min(i + u, lenD - 1)].x & 255;
#pragma unroll
        for (int u = 0; u < 4; ++u)
            if (i + u < lenD) atomicAdd(&deg[lo4[u]], 1);
    }
    __syncthreads();
    loff[t] = deg[t];
    __syncthreads();
    for (int o = 1; o < 256; o <<= 1) {
        int u = (t >= o) ? loff[t - o] : 0;
        __syncthreads();
        loff[t] += u;
        __syncthreads();
    }
    loff[t] -= deg[t];
    __syncthreads();
    int n = b * 256 + t;
    if (n < nN) {
        row_start[n] = begD + loff[t];
        norm_dst[n] = rsqrtf((float)max(deg[t], 1));
    }
    if (b == 0 && t == 0) row_start[nN] = nE;
    for (int i = 0; i < lenD; i += 4) {          // batched placement pass
        int2 r4[4];
#pragma unroll
        for (int u = 0; u < 4; ++u)
            r4[u] = partD[offD + min(i + u, lenD - 1)];
#pragma unroll
        for (int u = 0; u < 4; ++u) {
            if (i + u < lenD) {
                int lo = r4[u].x & 255;
                int pos = atomicAdd(&cnt[lo], 1);
                int idx = begD + loff[lo] + pos;
                csr_src[idx] = r4[u].x >> 8;
                unsigned uw = (unsigned)r4[u].y;
                csr_w[idx] = (unsigned short)((uw + 0x7fffu + ((uw >> 16) & 1u)) >> 16);
            }
        }
    }
    // ---- src side: per-run byte counts -> norm_src ----
    __syncthreads();
    deg[t] = 0;
    __syncthreads();
    int lenS = gHs[b * G1 + t + 1] - gHs[b * G1 + t];
    size_t offS = (size_t)t * chunk + gLocS[t * 256 + b];
    for (int i = 0; i < lenS; i += 8) {          // batched: 8 byte-loads in flight
        int v8[8];
#pragma unroll
        for (int u = 0; u < 8; ++u)
            v8[u] = partS[offS + min(i + u, lenS - 1)];
#pragma unroll
        for (int u = 0; u < 8; ++u)
            if (i + u < lenS) atomicAdd(&deg[v8[u]], 1);
    }
    __syncthreads();
    if (n < nN) norm_src[n] = rsqrtf((float)max(deg[t], 1));
}

// xw[n] = bf16( (x[n]*norm_src[n]) @ W1 )
__global__ __launch_bounds__(256) void xw_mm(const float* __restrict__ x,
    const float* __restrict__ norm_src, const float* __restrict__ W1,
    unsigned* __restrict__ xw, int nN) {
    __shared__ float sW[64 * 64];
    __shared__ float srow[4][64];
    int t = threadIdx.x;
    for (int i = t; i < 64 * 64; i += 256) sW[i] = W1[i];
    __syncthreads();
    int wid = t >> 6, k = t & 63;
    int base = blockIdx.x * 32;
    for (int it = 0; it < 8; ++it) {
        int n = base + it * 4 + wid;
        if (n >= nN) break;
        srow[wid][k] = x[((size_t)n << 6) + k] * norm_src[n];
        float acc0 = 0.f, acc1 = 0.f;
#pragma unroll
        for (int i = 0; i < 64; i += 2) {
            acc0 += srow[wid][i] * sW[i * 64 + k];
            acc1 += srow[wid][i + 1] * sW[(i + 1) * 64 + k];
        }
        float outv = acc0 + acc1;
        float other = __shfl_xor(outv, 1, 64);
        if ((k & 1) == 0) xw[((size_t)n << 5) + (k >> 1)] = bfpack(outv, other);
    }
}

// ---------------------------------------------------------------------------
// Fused layer1 gather + layer2 dense, 2-deep software pipeline over the wave's
// 4 nodes (measured optimum: 32-batch [r5] and 4-deep [r9] both regressed).
// Quarter-wave per edge (16 lanes x uint2 = 128B row), 24-edge clamped
// batches, serial remainder for long rows.
// ---------------------------------------------------------------------------
#define LCSR(P, bg, en) { \
    int last_ = max((en) - 1, 0); \
    _Pragma("unroll") \
    for (int u = 0; u < 6; ++u) { \
        int sl = (bg) + q + 4 * u; \
        int slc = (sl < (en)) ? sl : last_; \
        P##s[u] = csr_src[slc]; \
        float wv = bfs(csr_w[slc]); \
        P##w[u] = (sl < (en)) ? wv : 0.f; \
    } }
#define LGAT(P) { \
    _Pragma("unroll") \
    for (int u = 0; u < 6; ++u) P##p[u] = xw2[((size_t)P##s[u] << 4) + j]; }
#define LFMA(P) { \
    _Pragma("unroll") \
    for (int u = 0; u < 6; ++u) { \
        a0 += P##w[u] * bflo(P##p[u].x); a1 += P##w[u] * bfhi(P##p[u].x); \
        a2 += P##w[u] * bflo(P##p[u].y); a3 += P##w[u] * bfhi(P##p[u].y); } }
#define REM(P, bg, en) { \
    for (int sl0 = (bg) + q + 24; sl0 < (en); sl0 += 24) { \
        int last_ = (en) - 1; \
        _Pragma("unroll") \
        for (int u = 0; u < 6; ++u) { \
            int sl = sl0 + 4 * u; \
            int slc = (sl < (en)) ? sl : last_; \
            P##s[u] = csr_src[slc]; \
            float wv = bfs(csr_w[slc]); \
            P##w[u] = (sl < (en)) ? wv : 0.f; } \
        _Pragma("unroll") \
        for (int u = 0; u < 6; ++u) P##p[u] = xw2[((size_t)P##s[u] << 4) + j]; \
        LFMA(P) } }
#define EPI(nd_, ns_, n_) { \
    a0 += __shfl_xor(a0, 16, 64); a0 += __shfl_xor(a0, 32, 64); \
    a1 += __shfl_xor(a1, 16, 64); a1 += __shfl_xor(a1, 32, 64); \
    a2 += __shfl_xor(a2, 16, 64); a2 += __shfl_xor(a2, 32, 64); \
    a3 += __shfl_xor(a3, 16, 64); a3 += __shfl_xor(a3, 32, 64); \
    if (q == 0) { \
        float4 v; \
        v.x = fmaxf(a0 * (nd_) + bv.x, 0.f) * (ns_); \
        v.y = fmaxf(a1 * (nd_) + bv.y, 0.f) * (ns_); \
        v.z = fmaxf(a2 * (nd_) + bv.z, 0.f) * (ns_); \
        v.w = fmaxf(a3 * (nd_) + bv.w, 0.f) * (ns_); \
        *reinterpret_cast<float4*>(&srow[wid][4 * j]) = v; } \
    { int jj = lane & 31, ib = lane & 32; \
      float c0 = 0.f, c1 = 0.f; \
      _Pragma("unroll") \
      for (int i = 0; i < 32; i += 2) { \
          c0 += srow[wid][ib + i] * sW[(ib + i) * NCLS + jj]; \
          c1 += srow[wid][ib + i + 1] * sW[(ib + i + 1) * NCLS + jj]; } \
      float part = c0 + c1; \
      part += __shfl_xor(part, 32, 64); \
      float other = __shfl_xor(part, 1, 64); \
      if (ib == 0 && (jj & 1) == 0 && (n_) < nN) \
          hw[((size_t)(n_) << 4) + (jj >> 1)] = bfpack(part, other); } }

__global__ __launch_bounds__(256) void gather1_mm(const unsigned* __restrict__ xw,
    const int* __restrict__ row_start, const int* __restrict__ csr_src,
    const unsigned short* __restrict__ csr_w, const float* __restrict__ norm_dst,
    const float* __restrict__ norm_src, const float* __restrict__ W2f,
    const float* __restrict__ b1, unsigned* __restrict__ hw, int nN) {
    __shared__ float sW[64 * NCLS];
    __shared__ float srow[4][64];
    __shared__ int rs[17];
    int t = threadIdx.x;
    int base = blockIdx.x * 16;
    for (int i = t; i < 64 * NCLS; i += 256) sW[i] = W2f[i];
    if (t < 17) rs[t] = row_start[min(base + t, nN)];
    __syncthreads();
    int wid = t >> 6, lane = t & 63;
    int q = lane >> 4, j = lane & 15;        // quarter-wave edge groups
    const uint2* xw2 = reinterpret_cast<const uint2*>(xw);
    float4 bv = reinterpret_cast<const float4*>(b1)[j];   // b1[4j..4j+3]
    int n0 = base + wid, n1 = n0 + 4, n2 = n0 + 8, n3 = n0 + 12;
    int nc = nN - 1;
    // hoisted per-node norms: off the critical path
    float nd0 = norm_dst[min(n0, nc)], ns0 = norm_src[min(n0, nc)];
    float nd1 = norm_dst[min(n1, nc)], ns1 = norm_src[min(n1, nc)];
    float nd2 = norm_dst[min(n2, nc)], ns2 = norm_src[min(n2, nc)];
    float nd3 = norm_dst[min(n3, nc)], ns3 = norm_src[min(n3, nc)];
    int r0b = __builtin_amdgcn_readfirstlane(rs[wid]);
    int r0e = __builtin_amdgcn_readfirstlane(rs[wid + 1]);
    int r1b = __builtin_amdgcn_readfirstlane(rs[wid + 4]);
    int r1e = __builtin_amdgcn_readfirstlane(rs[wid + 5]);
    int r2b = __builtin_amdgcn_readfirstlane(rs[wid + 8]);
    int r2e = __builtin_amdgcn_readfirstlane(rs[wid + 9]);
    int r3b = __builtin_amdgcn_readfirstlane(rs[wid + 12]);
    int r3e = __builtin_amdgcn_readfirstlane(rs[wid + 13]);
    int As[6]; float Aw[6]; uint2 Ap[6];
    int Bs[6]; float Bw[6]; uint2 Bp[6];
    float a0, a1, a2, a3;
    // prologue: node0 + node1 memory phases overlap
    LCSR(A, r0b, r0e)
    LGAT(A)
    LCSR(B, r1b, r1e)
    LGAT(B)
    // node0
    a0 = a1 = a2 = a3 = 0.f;
    LFMA(A)
    REM(A, r0b, r0e)
    LCSR(A, r2b, r2e)          // csr(n2) flies under epilogue0
    EPI(nd0, ns0, n0)
    LGAT(A)                    // gathers(n2) fly under node1 processing
    // node1
    a0 = a1 = a2 = a3 = 0.f;
    LFMA(B)
    REM(B, r1b, r1e)
    LCSR(B, r3b, r3e)
    EPI(nd1, ns1, n1)
    LGAT(B)
    // node2
    a0 = a1 = a2 = a3 = 0.f;
    LFMA(A)
    REM(A, r2b, r2e)
    EPI(nd2, ns2, n2)
    // node3
    a0 = a1 = a2 = a3 = 0.f;
    LFMA(B)
    REM(B, r3b, r3e)
    EPI(nd3, ns3, n3)
}

// ---------------------------------------------------------------------------
// gather2 + pool accumulate: per-node agg goes straight into a per-block
// [64][32] LDS graph accumulator (f32, LDS atomics — nodes are graph-sorted,
// ~1-2 graphs/block), flushed with device-scope global atomicAdd. NO fence,
// NO ticket (round-6 lesson: intra-kernel agent-scope release = per-block L2
// writeback on 8 XCDs). Finalization is a separate tiny kernel; the stream's
// kernel boundary provides cross-XCD visibility. f32 pooling also drops the
// agg2 bf16 rounding -> absmax improves.
// Eighth-wave per edge (8 lanes x uint2 = 64B row), 24-edge clamped batches,
// 2-deep pipeline over the wave's 4 nodes.
// ---------------------------------------------------------------------------
#define LCSR2(P, bg, en) { \
    int last_ = max((en) - 1, 0); \
    _Pragma("unroll") \
    for (int u = 0; u < 3; ++u) { \
        int sl = (bg) + o + 8 * u; \
        int slc = (sl < (en)) ? sl : last_; \
        P##s[u] = csr_src[slc]; \
        float wv = bfs(csr_w[slc]); \
        P##w[u] = (sl < (en)) ? wv : 0.f; \
    } }
#define LGAT2(P) { \
    _Pragma("unroll") \
    for (int u = 0; u < 3; ++u) P##p[u] = hw2[((size_t)P##s[u] << 3) + j]; }
#define LFMA2(P) { \
    _Pragma("unroll") \
    for (int u = 0; u < 3; ++u) { \
        a0 += P##w[u] * bflo(P##p[u].x); a1 += P##w[u] * bfhi(P##p[u].x); \
        a2 += P##w[u] * bflo(P##p[u].y); a3 += P##w[u] * bfhi(P##p[u].y); } }
#define REM2(P, bg, en) { \
    for (int sl0 = (bg) + o + 24; sl0 < (en); sl0 += 24) { \
        int last_ = (en) - 1; \
        _Pragma("unroll") \
        for (int u = 0; u < 3; ++u) { \
            int sl = sl0 + 8 * u; \
            int slc = (sl < (en)) ? sl : last_; \
            P##s[u] = csr_src[slc]; \
            float wv = bfs(csr_w[slc]); \
            P##w[u] = (sl < (en)) ? wv : 0.f; } \
        _Pragma("unroll") \
        for (int u = 0; u < 3; ++u) P##p[u] = hw2[((size_t)P##s[u] << 3) + j]; \
        LFMA2(P) } }
#define EPI2(nd_, g_, n_) { \
    a0 += __shfl_xor(a0, 8, 64); a0 += __shfl_xor(a0, 16, 64); a0 += __shfl_xor(a0, 32, 64); \
    a1 += __shfl_xor(a1, 8, 64); a1 += __shfl_xor(a1, 16, 64); a1 += __shfl_xor(a1, 32, 64); \
    a2 += __shfl_xor(a2, 8, 64); a2 += __shfl_xor(a2, 16, 64); a2 += __shfl_xor(a2, 32, 64); \
    a3 += __shfl_xor(a3, 8, 64); a3 += __shfl_xor(a3, 16, 64); a3 += __shfl_xor(a3, 32, 64); \
    if (lane < 8 && (n_) < nN) { \
        atomicAdd(&gacc[(g_) * NCLS + 4 * j + 0], a0 * (nd_)); \
        atomicAdd(&gacc[(g_) * NCLS + 4 * j + 1], a1 * (nd_)); \
        atomicAdd(&gacc[(g_) * NCLS + 4 * j + 2], a2 * (nd_)); \
        atomicAdd(&gacc[(g_) * NCLS + 4 * j + 3], a3 * (nd_)); } }

__global__ __launch_bounds__(256) void gather2_acc(const unsigned* __restrict__ hw,
    const int* __restrict__ row_start, const int* __restrict__ csr_src,
    const unsigned short* __restrict__ csr_w, const float* __restrict__ norm_dst,
    const int* __restrict__ ng, float* __restrict__ gout, int nN) {
    __shared__ float gacc[NGRAPHS * NCLS];   // 8KB per-block graph accumulator
    __shared__ int rs[17];
    int t = threadIdx.x;
    int base = blockIdx.x * 16;
    for (int i = t; i < NGRAPHS * NCLS; i += 256) gacc[i] = 0.f;
    if (t < 17) rs[t] = row_start[min(base + t, nN)];
    __syncthreads();
    int wid = t >> 6, lane = t & 63;
    int o = lane >> 3, j = lane & 7;         // eighth-wave edge groups
    const uint2* hw2 = reinterpret_cast<const uint2*>(hw);
    int n0 = base + wid, n1 = n0 + 4, n2 = n0 + 8, n3 = n0 + 12;
    int nc = nN - 1;
    float nd0 = norm_dst[min(n0, nc)], nd1 = norm_dst[min(n1, nc)];
    float nd2 = norm_dst[min(n2, nc)], nd3 = norm_dst[min(n3, nc)];
    int g0 = ng[min(n0, nc)], g1 = ng[min(n1, nc)];
    int g2 = ng[min(n2, nc)], g3 = ng[min(n3, nc)];
    int r0b = __builtin_amdgcn_readfirstlane(rs[wid]);
    int r0e = __builtin_amdgcn_readfirstlane(rs[wid + 1]);
    int r1b = __builtin_amdgcn_readfirstlane(rs[wid + 4]);
    int r1e = __builtin_amdgcn_readfirstlane(rs[wid + 5]);
    int r2b = __builtin_amdgcn_readfirstlane(rs[wid + 8]);
    int r2e = __builtin_amdgcn_readfirstlane(rs[wid + 9]);
    int r3b = __builtin_amdgcn_readfirstlane(rs[wid + 12]);
    int r3e = __builtin_amdgcn_readfirstlane(rs[wid + 13]);
    int As[3]; float Aw[3]; uint2 Ap[3];
    int Bs[3]; float Bw[3]; uint2 Bp[3];
    float a0, a1, a2, a3;
    LCSR2(A, r0b, r0e)
    LGAT2(A)
    LCSR2(B, r1b, r1e)
    LGAT2(B)
    // node0
    a0 = a1 = a2 = a3 = 0.f;
    LFMA2(A)
    REM2(A, r0b, r0e)
    LCSR2(A, r2b, r2e)
    EPI2(nd0, g0, n0)
    LGAT2(A)
    // node1
    a0 = a1 = a2 = a3 = 0.f;
    LFMA2(B)
    REM2(B, r1b, r1e)
    LCSR2(B, r3b, r3e)
    EPI2(nd1, g1, n1)
    LGAT2(B)
    // node2
    a0 = a1 = a2 = a3 = 0.f;
    LFMA2(A)
    REM2(A, r2b, r2e)
    EPI2(nd2, g2, n2)
    // node3
    a0 = a1 = a2 = a3 = 0.f;
    LFMA2(B)
    REM2(B, r3b, r3e)
    EPI2(nd3, g3, n3)
    // ---- flush nonzero cells (device-scope atomics; no fence, no ticket) ----
    __syncthreads();
    for (int i = t; i < NGRAPHS * NCLS; i += 256) {
        float v = gacc[i];
        if (v != 0.f) atomicAdd(&gout[i], v);
    }
}

// finalize: tiny 1-block kernel after gather2_acc completes (stream boundary
// gives cross-XCD visibility of the atomic sums).
__global__ __launch_bounds__(256) void finalize_out(const float* __restrict__ gout,
    const int* __restrict__ ng, const float* __restrict__ b2,
    float* __restrict__ out, int nN) {
    __shared__ int cnts[NGRAPHS];
    int t = threadIdx.x;
    if (t < NGRAPHS) {
        int g = t;
        int lo = 0, hi = nN;
        while (lo < hi) { int m = (lo + hi) >> 1; if (ng[m] < g) lo = m + 1; else hi = m; }
        int lb = lo;
        lo = 0; hi = nN;
        while (lo < hi) { int m = (lo + hi) >> 1; if (ng[m] < g + 1) lo = m + 1; else hi = m; }
        cnts[g] = lo - lb;
    }
    __syncthreads();
    for (int i = t; i < NGRAPHS * NCLS; i += 256) {
        int g = i >> 5, f = i & 31;
        float cnt = (float)cnts[g];
        out[i] = (gout[i] + b2[f] * cnt) / fmaxf(cnt, 1.f);
    }
}

extern "C" void kernel_launch(void* const* d_in, const int* in_sizes, int n_in,
                              void* d_out, int out_size, void* d_ws, size_t ws_size,
                              hipStream_t stream) {
    const float* x   = (const float*)d_in[0];
    const float* eh  = (const float*)d_in[1];
    const int*   src = (const int*)d_in[2];
    const int*   dst = (const int*)d_in[3];
    const int*   ng  = (const int*)d_in[4];
    const float* W1  = (const float*)d_in[5];
    const float* b1  = (const float*)d_in[6];
    const float* W2  = (const float*)d_in[7];
    const float* b2  = (const float*)d_in[8];
    const float* mu  = (const float*)d_in[9];
    const float* sg  = (const float*)d_in[10];
    const int nN = in_sizes[0] / 64;
    const int nE = in_sizes[1];
    const int NBUK = (nN + 255) / 256;
    const int chunk = (nE + G1 - 1) / G1;

    // Workspace. Every cell read is written first (gout zeroed in part_scan).
    char* wsb = (char*)d_ws;
    int* gHd = (int*)wsb;                                 // 65537
    int* gHs = gHd + 65537;                               // 65537
    int* gLocD = gHs + 65537;                             // 65536
    int* gLocS = gLocD + 65536;                           // 65536
    int* row_start = gLocS + 65536;                       // nN+1
    float* norm_src = (float*)(row_start + nN + 1);       // nN
    float* norm_dst = norm_src + nN;                      // nN
    float* gout = norm_dst + nN;                          // 64*32
    size_t off = (size_t)((char*)(gout + NGRAPHS * NCLS) - wsb);
    off = (off + 15) & ~(size_t)15;
    int2* partD = (int2*)(wsb + off);                     // G1*chunk int2
    unsigned char* partS = (unsigned char*)(partD + (size_t)G1 * chunk); // G1*chunk
    off = (size_t)((char*)(partS + (size_t)G1 * chunk) - wsb);
    off = (off + 15) & ~(size_t)15;
    int* csr_src = (int*)(wsb + off);                     // nE
    unsigned short* csr_w = (unsigned short*)(csr_src + nE); // nE
    off = (size_t)((char*)(csr_w + nE) - wsb);
    off = (off + 15) & ~(size_t)15;
    unsigned* xw   = (unsigned*)(wsb + off);              // nN*32
    unsigned* hw   = xw + (size_t)nN * 32;                // nN*16

    part_hist_scatter<<<G1, 256, 0, stream>>>(eh, src, dst, mu, sg, gHd, gHs,
                                              gLocD, gLocS, partD, partS, nE);
    part_scan<<<2, 1024, 0, stream>>>(gHd, gHs, gout);
    bucket_build<<<NBUK, 256, 0, stream>>>(partD, partS, gHd, gHs, gLocD, gLocS,
                                           csr_src, csr_w, row_start,
                                           norm_dst, norm_src, nN, nE);
    xw_mm<<<(nN + 31) / 32, 256, 0, stream>>>(x, norm_src, W1, xw, nN);
    gather1_mm<<<(nN + 15) / 16, 256, 0, stream>>>(xw, row_start, csr_src, csr_w,
                                                   norm_dst, norm_src, W2, b1, hw, nN);
    gather2_acc<<<(nN + 15) / 16, 256, 0, stream>>>(hw, row_start, csr_src, csr_w,
                                                    norm_dst, ng, gout, nN);
    finalize_out<<<1, 256, 0, stream>>>(gout, ng, b2, (float*)d_out, nN);

    (void)n_in; (void)out_size; (void)ws_size;
}